// Round 14
// baseline (6120.144 us; speedup 1.0000x reference)
//
#include <hip/hip_runtime.h>
#include <cstdio>

typedef __bf16 bf16x8 __attribute__((ext_vector_type(8)));
typedef float f32x4 __attribute__((ext_vector_type(4)));

#define DEV __device__ __forceinline__

DEV short f2bf(float f) {
    unsigned u = __builtin_bit_cast(unsigned, f);
    u += 0x7fffu + ((u >> 16) & 1u);   // RNE
    return (short)(u >> 16);
}
DEV float bf2f(short s) {
    unsigned u = ((unsigned)(unsigned short)s) << 16;
    return __builtin_bit_cast(float, u);
}
DEV float sigmoidf_(float x) { return 1.0f / (1.0f + __expf(-x)); }
DEV float tanhf_(float x) { float e = __expf(2.0f * x); return 1.0f - 2.0f / (e + 1.0f); }

DEV void gload_lds16(const void* g, void* l) {
    __builtin_amdgcn_global_load_lds(
        (__attribute__((address_space(1))) void*)(g),
        (__attribute__((address_space(3))) void*)(l), 16, 0, 0);
}
DEV f32x4 mfma16(bf16x8 a, bf16x8 b, f32x4 c) {
    return __builtin_amdgcn_mfma_f32_16x16x32_bf16(a, b, c, 0, 0, 0);
}
DEV unsigned ald(const unsigned* p) {
    return __hip_atomic_load(p, __ATOMIC_RELAXED, __HIP_MEMORY_SCOPE_AGENT);
}
DEV unsigned long long ald64(const void* p) {
    return __hip_atomic_load((const unsigned long long*)p, __ATOMIC_RELAXED, __HIP_MEMORY_SCOPE_AGENT);
}
DEV void ast64(void* p, unsigned long long v) {
    __hip_atomic_store((unsigned long long*)p, v, __ATOMIC_RELAXED, __HIP_MEMORY_SCOPE_AGENT);
}
DEV void ast32(void* p, unsigned v) {
    __hip_atomic_store((unsigned*)p, v, __ATOMIC_RELAXED, __HIP_MEMORY_SCOPE_AGENT);
}
DEV void aadd(unsigned* p, unsigned v) {
    __hip_atomic_fetch_add(p, v, __ATOMIC_RELAXED, __HIP_MEMORY_SCOPE_AGENT);
}

// ---------------- f32 -> bf16 convert ----------------
__global__ void f2bf_vec(const float* __restrict__ in, short* __restrict__ out, int n4) {
    int i = blockIdx.x * 256 + threadIdx.x;
    if (i >= n4) return;
    float4 v = reinterpret_cast<const float4*>(in)[i];
    short4 o;
    o.x = f2bf(v.x); o.y = f2bf(v.y); o.z = f2bf(v.z); o.w = f2bf(v.w);
    reinterpret_cast<short4*>(out)[i] = o;
}

// ---------------- pack Wh [1536][512] f32 into MFMA B-fragment order ----------------
__global__ void pack_wh(const float* __restrict__ Wh, short* __restrict__ Wp) {
    int tile = blockIdx.x, kk = blockIdx.y, l = threadIdx.x;  // 96 x 16, 64 thr
    int n = tile * 16 + (l & 15);
    int k0 = kk * 32 + (l >> 4) * 8;
    const float* src = Wh + (size_t)n * 512 + k0;
    short o[8];
#pragma unroll
    for (int e = 0; e < 8; e++) o[e] = f2bf(src[e]);
    *(int4*)(Wp + ((size_t)(tile * 16 + kk) * 64 + l) * 8) = *(int4*)o;
}

enum { A_XW1 = 0, A_UAW = 1, A_UAS = 2, A_XW2 = 3 };

// ---------------- generic 128x128 tile GEMM, coherent C via padded LDS tile ----------
template<int MODE>
DEV void gemm_tile(short* Als, short* Bls, short* Ct, int m0, int n0,
                   const short* Abase, const short* A2,
                   const int* tok0, const int* tok1,
                   const short* W, const float* bias, short* C, int N, int K)
{
    int tid = threadIdx.x;
    int l = tid & 63, w = tid >> 6;
    int wm = (w >> 1) * 64, wn = (w & 1) * 64;
    int kc = (tid & 7) * 8;

    const short* arow[4];
#pragma unroll
    for (int i = 0; i < 4; i++) {
        int gm = m0 + i * 32 + (tid >> 3);
        if (MODE == A_XW1) {
            int t = gm >> 8, s = gm & 255;
            int tok = (s < 128) ? tok0[s * 256 + t] : tok1[(s - 128) * 256 + t];
            arow[i] = Abase + (size_t)tok * 512;
        } else if (MODE == A_UAW) {
            int t = gm >> 7, b = gm & 127;
            arow[i] = Abase + (size_t)tok0[b * 256 + t] * 512;
        } else if (MODE == A_UAS) {
            int t = gm >> 7, b = gm & 127;
            arow[i] = Abase + ((size_t)t * 256 + b) * 512;
        } else {
            arow[i] = Abase + (size_t)gm * 512;
        }
    }

    f32x4 acc[4][4] = {};
    for (int kt = 0; kt < K; kt += 64) {
#pragma unroll
        for (int i = 0; i < 4; i++) {
            const short* asrc;
            if (MODE == A_XW2) {
                int gm = m0 + i * 32 + (tid >> 3);
                const short* base = (kt < 512) ? Abase : A2;
                asrc = base + (size_t)gm * 512 + (kt & 511) + kc;
            } else {
                asrc = arow[i] + kt + kc;
            }
            gload_lds16(asrc, Als + i * 2048 + tid * 8);
        }
#pragma unroll
        for (int i = 0; i < 4; i++)
            gload_lds16(W + (size_t)(n0 + i * 32 + (tid >> 3)) * K + kt + kc,
                        Bls + i * 2048 + tid * 8);
        __syncthreads();
#pragma unroll
        for (int kk = 0; kk < 2; kk++) {
            int ko = kk * 32 + (l >> 4) * 8;
            bf16x8 af[4], bfr[4];
#pragma unroll
            for (int mi = 0; mi < 4; mi++)
                af[mi] = *(const bf16x8*)&Als[(wm + mi * 16 + (l & 15)) * 64 + ko];
#pragma unroll
            for (int ni = 0; ni < 4; ni++)
                bfr[ni] = *(const bf16x8*)&Bls[(wn + ni * 16 + (l & 15)) * 64 + ko];
#pragma unroll
            for (int mi = 0; mi < 4; mi++)
#pragma unroll
                for (int ni = 0; ni < 4; ni++)
                    acc[mi][ni] = mfma16(af[mi], bfr[ni], acc[mi][ni]);
        }
        __syncthreads();
    }
#pragma unroll
    for (int ni = 0; ni < 4; ni++) {
        float bv = bias[n0 + wn + ni * 16 + (l & 15)];
#pragma unroll
        for (int mi = 0; mi < 4; mi++)
#pragma unroll
            for (int jj = 0; jj < 4; jj++)
                Ct[(wm + mi * 16 + (l >> 4) * 4 + jj) * 132 + wn + ni * 16 + (l & 15)] =
                    f2bf(acc[mi][ni][jj] + bv);
    }
    __syncthreads();
    for (int r = 0; r < 16; r++) {
        int idx = r * 256 + tid;
        int row = idx >> 5, cc = idx & 31;
        unsigned long long val = *(const unsigned long long*)(Ct + row * 132 + cc * 4);
        ast64(C + (size_t)(m0 + row) * N + n0 + cc * 4, val);
    }
    __syncthreads();   // all threads' coherent stores drained
}

// ---------------- attention building blocks (device) ----------------
DEV void embed_sum_dev(const short* ebf, const int* tok, float* out, int b) {
    int d = threadIdx.x;
    float a0 = 0.f, a1 = 0.f;
    for (int t = 0; t < 256; t++) {
        const short* row = ebf + (size_t)tok[b * 256 + t] * 512;
        a0 += bf2f(row[d]); a1 += bf2f(row[d + 256]);
    }
    ast32(&out[b * 512 + d], __builtin_bit_cast(unsigned, a0));
    ast32(&out[b * 512 + d + 256], __builtin_bit_cast(unsigned, a1));
}
DEV void hall_sum_dev(const short* h_all, float* out, int b) {
    int d = threadIdx.x;
    float a0 = 0.f, a1 = 0.f;
    for (int t = 0; t < 256; t++) {
        const short* row = h_all + ((size_t)t * 256 + b) * 512;
        a0 += bf2f(row[d]); a1 += bf2f(row[d + 256]);
    }
    ast32(&out[b * 512 + d], __builtin_bit_cast(unsigned, a0));
    ast32(&out[b * 512 + d + 256], __builtin_bit_cast(unsigned, a1));
}

template<int WORD, int COHOUT>
DEV void combine4(int bb, const short* uA, const short* rsrc, const int* rtok,
                  const float* usum, const float* Wv, short* ctx)
{
    int l = threadIdx.x & 63, w = threadIdx.x >> 6;
    int m = bb * 4 + w;
    int t = m >> 7, b = m & 127;
    const short* rrow;
    if (WORD) rrow = rsrc + (size_t)rtok[b * 256 + t] * 512;
    else      rrow = rsrc + ((size_t)t * 256 + 128 + b) * 512;
    int d0 = l * 8;
    short ru[8], uu[8];
    *(int4*)ru = *(const int4*)(rrow + d0);
    *(unsigned long long*)uu       = ald64(uA + (size_t)m * 512 + d0);
    *((unsigned long long*)uu + 1) = ald64(uA + (size_t)m * 512 + d0 + 4);
    float rv[8], dot = 0.f;
#pragma unroll
    for (int i = 0; i < 8; i++) { rv[i] = bf2f(ru[i]); dot += rv[i] * bf2f(uu[i]); }
#pragma unroll
    for (int off = 32; off >= 1; off >>= 1) dot += __shfl_xor(dot, off);
    float tw = tanhf_(dot);
    float us[8];
#pragma unroll
    for (int i = 0; i < 4; i++) {
        unsigned long long uv = ald64(usum + b * 512 + d0 + i * 2);
        us[i * 2]     = __builtin_bit_cast(float, (unsigned)(uv & 0xffffffffu));
        us[i * 2 + 1] = __builtin_bit_cast(float, (unsigned)(uv >> 32));
    }
    float e[8], se = 0.f;
#pragma unroll
    for (int i = 0; i < 8; i++) { e[i] = __expf(tw * Wv[d0 + i]); se += e[i]; }
#pragma unroll
    for (int off = 32; off >= 1; off >>= 1) se += __shfl_xor(se, off);
    float inv = 1.f / se;
    short ov[8];
#pragma unroll
    for (int i = 0; i < 8; i++) ov[i] = f2bf(e[i] * inv * us[i] * rv[i]);
    if (COHOUT) {
        ast64(ctx + (size_t)m * 512 + d0,     *(unsigned long long*)ov);
        ast64(ctx + (size_t)m * 512 + d0 + 4, *((unsigned long long*)ov + 1));
    } else {
        *(int4*)(ctx + (size_t)m * 512 + d0) = *(int4*)ov;
    }
}

// ---------------- scan role: self-validating tagged h exchange ----------------
// Tagged h buffers: [S][512] u32 words, word = bf16(h) | tag<<16, tag = tagbase+t+1.
// Consumer polls the DATA (32x 8B loads/thread, per-word tag check + re-poll) —
// no done-words, no drain, no publish; fire-and-forget tagged stores.
// Write-after-read safety: reading all peers' h(t-1) tags proves every peer
// consumed h(t-2), so overwriting buf[t&1] is safe (same induction as v9-v13).
template<int WRITE_ALL>
DEV void scan_role(char* smem, int cb, int rg,
                   const short* xW, const short* Wp, const float* bh,
                   unsigned* hbt0, unsigned* hbt1,
                   short* h_all, float* h_final,
                   unsigned* slice_cnt, int tps, int S, int T, int tagbase)
{
    char* wl = smem;               // 96 KB Wh fragments
    char* sl = smem + 98304;       // 32 KB h value slab, XOR-swizzled
    int tid = threadIdx.x;
    int r0 = rg * 32;
    int w = tid >> 6, l = tid & 63;
    int rt = w >> 1, ct = w & 1;
    int lrow = l & 15, lq = l >> 4;
    int colg = cb * 32 + ct * 16 + lrow;
    const unsigned long long TMASK = 0xFFFF0000FFFF0000ULL;

    for (int rr = 0; rr < 24; rr++) {
        int flat = rr * 256 + tid;
        int lane = flat & 63, kk = (flat >> 6) & 15, lg = flat >> 10;
        int g = lg >> 1, c2 = lg & 1;
        gload_lds16(Wp + (((size_t)(g * 32 + cb * 2 + c2) * 16 + kk) * 64 + lane) * 8,
                    wl + flat * 16);
    }
    float bhv[3];
#pragma unroll
    for (int g = 0; g < 3; g++) bhv[g] = bh[g * 512 + colg];
    __syncthreads();   // drains Wh DMA

    float hp[4] = {};

    for (int t = 0; t < T; t++) {
        // poll phase: fused detect+load on tagged slab (t>0)
        if (t > 0) {
            const unsigned* hbp = ((t & 1) ? hbt0 : hbt1) + (size_t)r0 * 512;
            const unsigned long long* sp = (const unsigned long long*)hbp;
            unsigned long long tg = (unsigned long long)(unsigned)(tagbase + t);
            unsigned long long pat = (tg << 16) | (tg << 48);
            unsigned long long v[32];
#pragma unroll
            for (int k = 0; k < 32; k++) v[k] = ald64(sp + k * 256 + tid);
#pragma unroll
            for (int k = 0; k < 32; k++) {
                while (((v[k] ^ pat) & TMASK) != 0ULL) {
                    __builtin_amdgcn_s_sleep(1);
                    v[k] = ald64(sp + k * 256 + tid);
                }
                unsigned lo = (unsigned)v[k] & 0xFFFFu;
                unsigned hi = (unsigned)(v[k] >> 32) & 0xFFFFu;
                *(unsigned*)(sl + k * 1024 + ((tid * 4) ^ ((k & 7) << 4))) = lo | (hi << 16);
            }
        }
        // xW slice gate (producers publish with drained stores then counter add)
        if (tid == 0) {
            while (ald(&slice_cnt[t]) < (unsigned)tps) __builtin_amdgcn_s_sleep(1);
        }
        __syncthreads();   // BAR1: slab values visible + slice gate observed

        short xrv[4], xzv[4], xnv[4];
        const short* xbase = xW + ((size_t)t * S + r0) * 1536 + colg;
#pragma unroll
        for (int j = 0; j < 4; j++) {
            const short* xp = xbase + (size_t)(rt * 16 + lq * 4 + j) * 1536;
            xrv[j] = xp[0]; xzv[j] = xp[512]; xnv[j] = xp[1024];
        }

        f32x4 acc[3] = {};
        if (t > 0) {
            bf16x8 afr[16];
            int ar = rt * 16 + lrow;
#pragma unroll
            for (int kk = 0; kk < 16; kk++) {
                int colb = kk * 64 + lq * 16;
                afr[kk] = *(const bf16x8*)(sl + ar * 1024 + (colb ^ ((ar & 7) << 4)));
            }
#pragma unroll
            for (int g = 0; g < 3; g++) {
                const char* bbase = wl + (size_t)((g * 2 + ct) * 16) * 1024 + l * 16;
#pragma unroll
                for (int kk = 0; kk < 16; kk++) {
                    bf16x8 bfr = *(const bf16x8*)(bbase + kk * 1024);
                    acc[g] = mfma16(afr[kk], bfr, acc[g]);
                }
            }
        }

        // gates + fire-and-forget tagged stores
        unsigned* hbn = ((t & 1) ? hbt1 : hbt0);
        unsigned tagw = (unsigned)(tagbase + t + 1) << 16;
        float hv[4];
#pragma unroll
        for (int j = 0; j < 4; j++) {
            float r = sigmoidf_(bf2f(xrv[j]) + bhv[0] + acc[0][j]);
            float z = sigmoidf_(bf2f(xzv[j]) + bhv[1] + acc[1][j]);
            float n = tanhf_(bf2f(xnv[j]) + r * (acc[2][j] + bhv[2]));
            hv[j] = (1.f - z) * n + z * hp[j];
            hp[j] = hv[j];
            short hb16 = f2bf(hv[j]);
            int row = r0 + rt * 16 + lq * 4 + j;
            ast32(hbn + (size_t)row * 512 + colg, tagw | (unsigned)(unsigned short)hb16);
            if (WRITE_ALL) h_all[((size_t)t * S + row) * 512 + colg] = hb16;
            else if (t == T - 1) h_final[(size_t)row * 512 + colg] = hv[j];
        }
        __syncthreads();   // BAR2: all waves done reading sl before next ds_write
    }
}

// ---------------- GRU1 fused: 128 scan + 128 producers (xW1 then word attention) -------
__global__ __launch_bounds__(256, 1) void gru_fused1(
    short* xW1, const short* __restrict__ Wp, const float* __restrict__ bh,
    unsigned* hbt0, unsigned* hbt1, short* __restrict__ h_all,
    unsigned* slc,
    const short* __restrict__ embed_bf, const int* __restrict__ ask,
    const int* __restrict__ answer, const short* __restrict__ Wi1b,
    const float* __restrict__ bi1,
    const int* __restrict__ askkw, const int* __restrict__ anskw,
    const short* __restrict__ Awb, const float* __restrict__ bw,
    float* usumW, short* uAb, const float* __restrict__ Ww, short* ctxW,
    unsigned* wcnt)
{
    __shared__ char smem[131072];
    int bid = blockIdx.x, tid = threadIdx.x;

    if (bid >= 128) {
        int pid = bid - 128;
        short* Als = (short*)smem;
        short* Bls = (short*)(smem + 16384);
        short* Ct  = (short*)(smem + 32768);
        for (int q = pid; q < 256 * 24; q += 128) {
            int slice = q / 24, j = q % 24;
            int m0 = (slice * 2 + (j >= 12 ? 1 : 0)) * 128, n0 = (j % 12) * 128;
            gemm_tile<A_XW1>(Als, Bls, Ct, m0, n0, embed_bf, nullptr, ask, answer,
                             Wi1b, bi1, xW1, 1536, 512);
            if (tid == 0) aadd(&slc[slice], 1u);
        }
        embed_sum_dev(embed_bf, askkw, usumW, pid);
        for (int k = 0; k < 8; k++) {
            int q = pid + k * 128;
            gemm_tile<A_UAW>(Als, Bls, Ct, (q >> 2) * 128, (q & 3) * 128,
                             embed_bf, nullptr, askkw, nullptr, Awb, bw, uAb, 512, 512);
        }
        if (tid == 0) {
            aadd(wcnt, 1u);
            while (ald(wcnt) < 128u) __builtin_amdgcn_s_sleep(1);
        }
        __syncthreads();
        for (int bb = pid * 64; bb < pid * 64 + 64; bb++)
            combine4<1, 0>(bb, uAb, embed_bf, anskw, usumW, Ww, ctxW);
        return;
    }
    scan_role<1>(smem, bid & 15, bid >> 4, xW1, Wp, bh, hbt0, hbt1, h_all, nullptr,
                 slc, 24, 256, 256, 0);
}

// ---------------- GRU2 fused: seq-attention pre-phase (all 256) + 64 scan + 192 prod ----
__global__ __launch_bounds__(256, 1) void gru_fused2(
    short* xW2, const short* __restrict__ Wp, const float* __restrict__ bh,
    unsigned* hbt0, unsigned* hbt1, float* __restrict__ h_final,
    unsigned* slc,
    const short* __restrict__ h_all, float* usumS, short* uAb,
    const short* __restrict__ Asb, const float* __restrict__ bs,
    const float* __restrict__ Ws, short* ctxS, const short* __restrict__ ctxW,
    const short* __restrict__ Wi2b, const float* __restrict__ bi2,
    unsigned* acnt, unsigned* ccnt)
{
    __shared__ char smem[131072];
    int bid = blockIdx.x, tid = threadIdx.x;
    short* Als = (short*)smem;
    short* Bls = (short*)(smem + 16384);
    short* Ct  = (short*)(smem + 32768);

    if (bid < 128) hall_sum_dev(h_all, usumS, bid);
    for (int k = 0; k < 4; k++) {
        int q = bid + k * 256;
        gemm_tile<A_UAS>(Als, Bls, Ct, (q >> 2) * 128, (q & 3) * 128,
                         h_all, nullptr, nullptr, nullptr, Asb, bs, uAb, 512, 512);
    }
    if (tid == 0) {
        aadd(acnt, 1u);
        while (ald(acnt) < 256u) __builtin_amdgcn_s_sleep(1);
    }
    __syncthreads();
    for (int bb = bid * 32; bb < bid * 32 + 32; bb++)
        combine4<0, 1>(bb, uAb, h_all, nullptr, usumS, Ws, ctxS);
    __syncthreads();                 // per-thread vmcnt(0): ctxS coherent stores drained
    if (tid == 0) aadd(ccnt, 1u);

    if (bid >= 64) {
        int pid = bid - 64;
        if (tid == 0) { while (ald(ccnt) < 256u) __builtin_amdgcn_s_sleep(1); }
        __syncthreads();
        for (int q = pid; q < 256 * 12; q += 192) {
            int slice = q / 12, j = q % 12;
            gemm_tile<A_XW2>(Als, Bls, Ct, slice * 128, j * 128,
                             ctxW, ctxS, nullptr, nullptr, Wi2b, bi2, xW2, 1536, 1024);
            if (tid == 0) aadd(&slc[slice], 1u);
        }
        return;
    }
    scan_role<0>(smem, bid & 15, bid >> 4, xW2, Wp, bh, hbt0, hbt1, nullptr, h_final,
                 slc, 12, 128, 256, 256);
}

// ---------------- final classifier + softmax ----------------
__global__ void final_head_k(const float* __restrict__ h2, const float* __restrict__ Wf,
                             const float* __restrict__ bfv, float* __restrict__ out) {
    int b = blockIdx.x, l = threadIdx.x;  // 64 threads
    float d0 = 0.f, d1 = 0.f;
    for (int k = l; k < 512; k += 64) {
        float h = h2[b * 512 + k];
        d0 += h * Wf[k];
        d1 += h * Wf[512 + k];
    }
#pragma unroll
    for (int off = 32; off >= 1; off >>= 1) { d0 += __shfl_xor(d0, off); d1 += __shfl_xor(d1, off); }
    if (l == 0) {
        float l0 = d0 + bfv[0], l1 = d1 + bfv[1];
        float mx = fmaxf(l0, l1);
        float e0 = __expf(l0 - mx), e1 = __expf(l1 - mx);
        float s = e0 + e1;
        out[b * 2] = e0 / s; out[b * 2 + 1] = e1 / s;
    }
}

extern "C" void kernel_launch(void* const* d_in, const int* in_sizes, int n_in,
                              void* d_out, int out_size, void* d_ws, size_t ws_size,
                              hipStream_t stream)
{
    const int* ask    = (const int*)d_in[0];
    const int* answer = (const int*)d_in[1];
    const int* askkw  = (const int*)d_in[2];
    const int* anskw  = (const int*)d_in[3];
    const float* embed = (const float*)d_in[4];
    const float* Wi1 = (const float*)d_in[5];
    const float* Wh1 = (const float*)d_in[6];
    const float* bi1 = (const float*)d_in[7];
    const float* bh1 = (const float*)d_in[8];
    const float* Aw  = (const float*)d_in[9];
    const float* bw  = (const float*)d_in[10];
    const float* Ww  = (const float*)d_in[11];
    const float* As  = (const float*)d_in[12];
    const float* bs  = (const float*)d_in[13];
    const float* Ws  = (const float*)d_in[14];
    const float* Wi2 = (const float*)d_in[15];
    const float* Wh2 = (const float*)d_in[16];
    const float* bi2 = (const float*)d_in[17];
    const float* bh2 = (const float*)d_in[18];
    const float* Wf  = (const float*)d_in[19];
    const float* bfv = (const float*)d_in[20];

    char* ws = (char*)d_ws;
    size_t off = 0;
    auto alloc = [&](size_t bytes) -> void* {
        void* p = (void*)(ws + off);
        off += (bytes + 255) & ~(size_t)255;
        return p;
    };
    short* embed_bf = (short*)alloc(50000ULL * 512 * 2);
    short* Wi1b = (short*)alloc(1536 * 512 * 2);
    short* Wp1  = (short*)alloc(1536 * 512 * 2);
    short* Awb  = (short*)alloc(512 * 512 * 2);
    short* Asb  = (short*)alloc(512 * 512 * 2);
    short* Wi2b = (short*)alloc(1536 * 1024 * 2);
    short* Wp2  = (short*)alloc(1536 * 512 * 2);
    char* X = (char*)alloc(201326592ULL);            // xW1 [256][256][1536] bf16
    short* xW1  = (short*)X;
    short* xW2  = (short*)X;                         // [256][128][1536] bf16 (xW1 dead)
    short* ctxS = (short*)(X + 100663296);           // X tail (lifetime-safe, round 13)
    short* uAb  = (short*)alloc(32768ULL * 512 * 2);
    short* ctxW = (short*)alloc(32768ULL * 512 * 2);
    short* h_all = (short*)alloc(256ULL * 256 * 512 * 2);
    unsigned* hbt0 = (unsigned*)alloc(256 * 512 * 4);  // tagged h buffers
    unsigned* hbt1 = (unsigned*)alloc(256 * 512 * 4);
    float* usumW = (float*)alloc(128 * 512 * 4);
    float* usumS = (float*)alloc(128 * 512 * 4);
    float* h2f   = (float*)alloc(128 * 512 * 4);
    unsigned* syncb = (unsigned*)alloc((256 + 256 + 96) * 4);
    unsigned* slc1  = syncb;
    unsigned* slc2  = syncb + 256;
    unsigned* wcnt1 = syncb + 512;
    unsigned* acnt2 = wcnt1 + 32;
    unsigned* ccnt2 = wcnt1 + 64;

    if (off > ws_size) {
        fprintf(stderr, "kernel_launch: workspace too small: need %zu have %zu\n", off, ws_size);
        return;
    }

    // zero sync state + tagged buffers (in-graph, every replay — tags would alias
    // across replays otherwise)
    hipMemsetAsync(syncb, 0, (256 + 256 + 96) * 4, stream);
    hipMemsetAsync(hbt0, 0, 256 * 512 * 4, stream);
    hipMemsetAsync(hbt1, 0, 256 * 512 * 4, stream);

    auto cv = [&](const float* src, short* dst, int n) {
        int n4 = n / 4;
        f2bf_vec<<<(n4 + 255) / 256, 256, 0, stream>>>(src, dst, n4);
    };
    cv(embed, embed_bf, 50000 * 512);
    cv(Wi1, Wi1b, 1536 * 512);
    cv(Aw, Awb, 512 * 512);
    cv(As, Asb, 512 * 512);
    cv(Wi2, Wi2b, 1536 * 1024);
    pack_wh<<<dim3(96, 16), 64, 0, stream>>>(Wh1, Wp1);
    pack_wh<<<dim3(96, 16), 64, 0, stream>>>(Wh2, Wp2);

    // GRU1 + xW1 producers + word attention
    {
        void* args[] = { (void*)&xW1, (void*)&Wp1, (void*)&bh1, (void*)&hbt0, (void*)&hbt1,
                         (void*)&h_all, (void*)&slc1,
                         (void*)&embed_bf, (void*)&ask, (void*)&answer, (void*)&Wi1b, (void*)&bi1,
                         (void*)&askkw, (void*)&anskw, (void*)&Awb, (void*)&bw,
                         (void*)&usumW, (void*)&uAb, (void*)&Ww, (void*)&ctxW, (void*)&wcnt1 };
        hipError_t e = hipLaunchCooperativeKernel(
            reinterpret_cast<void*>(&gru_fused1), dim3(256), dim3(256), args, 0, stream);
        if (e != hipSuccess)
            gru_fused1<<<256, 256, 0, stream>>>(
                xW1, Wp1, bh1, hbt0, hbt1, h_all, slc1,
                embed_bf, ask, answer, Wi1b, bi1,
                askkw, anskw, Awb, bw, usumW, uAb, Ww, ctxW, wcnt1);
    }

    // GRU2 + seq-attention pre-phase + xW2 producers
    {
        void* args[] = { (void*)&xW2, (void*)&Wp2, (void*)&bh2, (void*)&hbt0, (void*)&hbt1,
                         (void*)&h2f, (void*)&slc2,
                         (void*)&h_all, (void*)&usumS, (void*)&uAb,
                         (void*)&Asb, (void*)&bs, (void*)&Ws, (void*)&ctxS, (void*)&ctxW,
                         (void*)&Wi2b, (void*)&bi2, (void*)&acnt2, (void*)&ccnt2 };
        hipError_t e = hipLaunchCooperativeKernel(
            reinterpret_cast<void*>(&gru_fused2), dim3(256), dim3(256), args, 0, stream);
        if (e != hipSuccess)
            gru_fused2<<<256, 256, 0, stream>>>(
                xW2, Wp2, bh2, hbt0, hbt1, h2f, slc2,
                h_all, usumS, uAb, Asb, bs, Ws, ctxS, ctxW, Wi2b, bi2, acnt2, ccnt2);
    }

    final_head_k<<<128, 64, 0, stream>>>(h2f, Wf, bfv, (float*)d_out);
}

// Round 15
// 1933.386 us; speedup vs baseline: 3.1655x; 3.1655x over previous
//
#include <hip/hip_runtime.h>
#include <cstdio>

typedef __bf16 bf16x8 __attribute__((ext_vector_type(8)));
typedef float f32x4 __attribute__((ext_vector_type(4)));

#define DEV __device__ __forceinline__

DEV short f2bf(float f) {
    unsigned u = __builtin_bit_cast(unsigned, f);
    u += 0x7fffu + ((u >> 16) & 1u);   // RNE
    return (short)(u >> 16);
}
DEV float bf2f(short s) {
    unsigned u = ((unsigned)(unsigned short)s) << 16;
    return __builtin_bit_cast(float, u);
}
DEV float sigmoidf_(float x) { return 1.0f / (1.0f + __expf(-x)); }
DEV float tanhf_(float x) { float e = __expf(2.0f * x); return 1.0f - 2.0f / (e + 1.0f); }

DEV void gload_lds16(const void* g, void* l) {
    __builtin_amdgcn_global_load_lds(
        (__attribute__((address_space(1))) void*)(g),
        (__attribute__((address_space(3))) void*)(l), 16, 0, 0);
}
DEV f32x4 mfma16(bf16x8 a, bf16x8 b, f32x4 c) {
    return __builtin_amdgcn_mfma_f32_16x16x32_bf16(a, b, c, 0, 0, 0);
}
DEV unsigned ald(const unsigned* p) {
    return __hip_atomic_load(p, __ATOMIC_RELAXED, __HIP_MEMORY_SCOPE_AGENT);
}
DEV unsigned long long ald64(const void* p) {
    return __hip_atomic_load((const unsigned long long*)p, __ATOMIC_RELAXED, __HIP_MEMORY_SCOPE_AGENT);
}
DEV void ast64(void* p, unsigned long long v) {
    __hip_atomic_store((unsigned long long*)p, v, __ATOMIC_RELAXED, __HIP_MEMORY_SCOPE_AGENT);
}
DEV void ast32(void* p, unsigned v) {
    __hip_atomic_store((unsigned*)p, v, __ATOMIC_RELAXED, __HIP_MEMORY_SCOPE_AGENT);
}
DEV void aadd(unsigned* p, unsigned v) {
    __hip_atomic_fetch_add(p, v, __ATOMIC_RELAXED, __HIP_MEMORY_SCOPE_AGENT);
}

// ---------------- f32 -> bf16 convert ----------------
__global__ void f2bf_vec(const float* __restrict__ in, short* __restrict__ out, int n4) {
    int i = blockIdx.x * 256 + threadIdx.x;
    if (i >= n4) return;
    float4 v = reinterpret_cast<const float4*>(in)[i];
    short4 o;
    o.x = f2bf(v.x); o.y = f2bf(v.y); o.z = f2bf(v.z); o.w = f2bf(v.w);
    reinterpret_cast<short4*>(out)[i] = o;
}

// ---------------- pack Wh [1536][512] f32 into MFMA B-fragment order ----------------
__global__ void pack_wh(const float* __restrict__ Wh, short* __restrict__ Wp) {
    int tile = blockIdx.x, kk = blockIdx.y, l = threadIdx.x;  // 96 x 16, 64 thr
    int n = tile * 16 + (l & 15);
    int k0 = kk * 32 + (l >> 4) * 8;
    const float* src = Wh + (size_t)n * 512 + k0;
    short o[8];
#pragma unroll
    for (int e = 0; e < 8; e++) o[e] = f2bf(src[e]);
    *(int4*)(Wp + ((size_t)(tile * 16 + kk) * 64 + l) * 8) = *(int4*)o;
}

enum { A_XW1 = 0, A_UAW = 1, A_UAS = 2, A_XW2 = 3 };

// ---------------- generic 128x128 tile GEMM, coherent C via padded LDS tile ----------
// Ct stride 132 shorts (264B rows): kills the 8-way bank aliasing of 128-short rows.
template<int MODE>
DEV void gemm_tile(short* Als, short* Bls, short* Ct, int m0, int n0,
                   const short* Abase, const short* A2,
                   const int* tok0, const int* tok1,
                   const short* W, const float* bias, short* C, int N, int K)
{
    int tid = threadIdx.x;
    int l = tid & 63, w = tid >> 6;
    int wm = (w >> 1) * 64, wn = (w & 1) * 64;
    int kc = (tid & 7) * 8;

    const short* arow[4];
#pragma unroll
    for (int i = 0; i < 4; i++) {
        int gm = m0 + i * 32 + (tid >> 3);
        if (MODE == A_XW1) {
            int t = gm >> 8, s = gm & 255;
            int tok = (s < 128) ? tok0[s * 256 + t] : tok1[(s - 128) * 256 + t];
            arow[i] = Abase + (size_t)tok * 512;
        } else if (MODE == A_UAW) {
            int t = gm >> 7, b = gm & 127;
            arow[i] = Abase + (size_t)tok0[b * 256 + t] * 512;
        } else if (MODE == A_UAS) {
            int t = gm >> 7, b = gm & 127;
            arow[i] = Abase + ((size_t)t * 256 + b) * 512;
        } else {
            arow[i] = Abase + (size_t)gm * 512;
        }
    }

    f32x4 acc[4][4] = {};
    for (int kt = 0; kt < K; kt += 64) {
#pragma unroll
        for (int i = 0; i < 4; i++) {
            const short* asrc;
            if (MODE == A_XW2) {
                int gm = m0 + i * 32 + (tid >> 3);
                const short* base = (kt < 512) ? Abase : A2;
                asrc = base + (size_t)gm * 512 + (kt & 511) + kc;
            } else {
                asrc = arow[i] + kt + kc;
            }
            gload_lds16(asrc, Als + i * 2048 + tid * 8);
        }
#pragma unroll
        for (int i = 0; i < 4; i++)
            gload_lds16(W + (size_t)(n0 + i * 32 + (tid >> 3)) * K + kt + kc,
                        Bls + i * 2048 + tid * 8);
        __syncthreads();
#pragma unroll
        for (int kk = 0; kk < 2; kk++) {
            int ko = kk * 32 + (l >> 4) * 8;
            bf16x8 af[4], bfr[4];
#pragma unroll
            for (int mi = 0; mi < 4; mi++)
                af[mi] = *(const bf16x8*)&Als[(wm + mi * 16 + (l & 15)) * 64 + ko];
#pragma unroll
            for (int ni = 0; ni < 4; ni++)
                bfr[ni] = *(const bf16x8*)&Bls[(wn + ni * 16 + (l & 15)) * 64 + ko];
#pragma unroll
            for (int mi = 0; mi < 4; mi++)
#pragma unroll
                for (int ni = 0; ni < 4; ni++)
                    acc[mi][ni] = mfma16(af[mi], bfr[ni], acc[mi][ni]);
        }
        __syncthreads();
    }
#pragma unroll
    for (int ni = 0; ni < 4; ni++) {
        float bv = bias[n0 + wn + ni * 16 + (l & 15)];
#pragma unroll
        for (int mi = 0; mi < 4; mi++)
#pragma unroll
            for (int jj = 0; jj < 4; jj++)
                Ct[(wm + mi * 16 + (l >> 4) * 4 + jj) * 132 + wn + ni * 16 + (l & 15)] =
                    f2bf(acc[mi][ni][jj] + bv);
    }
    __syncthreads();
    for (int r = 0; r < 16; r++) {
        int idx = r * 256 + tid;
        int row = idx >> 5, cc = idx & 31;
        unsigned long long val = *(const unsigned long long*)(Ct + row * 132 + cc * 4);
        ast64(C + (size_t)(m0 + row) * N + n0 + cc * 4, val);
    }
    __syncthreads();   // all threads' coherent stores drained
}

// ---------------- attention building blocks (device) ----------------
DEV void embed_sum_dev(const short* ebf, const int* tok, float* out, int b) {
    int d = threadIdx.x;
    float a0 = 0.f, a1 = 0.f;
    for (int t = 0; t < 256; t++) {
        const short* row = ebf + (size_t)tok[b * 256 + t] * 512;
        a0 += bf2f(row[d]); a1 += bf2f(row[d + 256]);
    }
    ast32(&out[b * 512 + d], __builtin_bit_cast(unsigned, a0));
    ast32(&out[b * 512 + d + 256], __builtin_bit_cast(unsigned, a1));
}
DEV void hall_sum_dev(const short* h_all, float* out, int b) {
    int d = threadIdx.x;
    float a0 = 0.f, a1 = 0.f;
    for (int t = 0; t < 256; t++) {
        const short* row = h_all + ((size_t)t * 256 + b) * 512;
        a0 += bf2f(row[d]); a1 += bf2f(row[d + 256]);
    }
    ast32(&out[b * 512 + d], __builtin_bit_cast(unsigned, a0));
    ast32(&out[b * 512 + d + 256], __builtin_bit_cast(unsigned, a1));
}

// one block-equivalent of the original attn_combine (4 m's, wave w -> m = bb*4+w)
// uA/usum: atomic reads (in-kernel atomic-written); rsrc: plain (kernel-boundary data).
template<int WORD, int COHOUT>
DEV void combine4(int bb, const short* uA, const short* rsrc, const int* rtok,
                  const float* usum, const float* Wv, short* ctx)
{
    int l = threadIdx.x & 63, w = threadIdx.x >> 6;
    int m = bb * 4 + w;
    int t = m >> 7, b = m & 127;
    const short* rrow;
    if (WORD) rrow = rsrc + (size_t)rtok[b * 256 + t] * 512;
    else      rrow = rsrc + ((size_t)t * 256 + 128 + b) * 512;
    int d0 = l * 8;
    short ru[8], uu[8];
    *(int4*)ru = *(const int4*)(rrow + d0);
    *(unsigned long long*)uu       = ald64(uA + (size_t)m * 512 + d0);
    *((unsigned long long*)uu + 1) = ald64(uA + (size_t)m * 512 + d0 + 4);
    float rv[8], dot = 0.f;
#pragma unroll
    for (int i = 0; i < 8; i++) { rv[i] = bf2f(ru[i]); dot += rv[i] * bf2f(uu[i]); }
#pragma unroll
    for (int off = 32; off >= 1; off >>= 1) dot += __shfl_xor(dot, off);
    float tw = tanhf_(dot);
    float us[8];
#pragma unroll
    for (int i = 0; i < 4; i++) {
        unsigned long long uv = ald64(usum + b * 512 + d0 + i * 2);
        us[i * 2]     = __builtin_bit_cast(float, (unsigned)(uv & 0xffffffffu));
        us[i * 2 + 1] = __builtin_bit_cast(float, (unsigned)(uv >> 32));
    }
    float e[8], se = 0.f;
#pragma unroll
    for (int i = 0; i < 8; i++) { e[i] = __expf(tw * Wv[d0 + i]); se += e[i]; }
#pragma unroll
    for (int off = 32; off >= 1; off >>= 1) se += __shfl_xor(se, off);
    float inv = 1.f / se;
    short ov[8];
#pragma unroll
    for (int i = 0; i < 8; i++) ov[i] = f2bf(e[i] * inv * us[i] * rv[i]);
    if (COHOUT) {
        ast64(ctx + (size_t)m * 512 + d0,     *(unsigned long long*)ov);
        ast64(ctx + (size_t)m * 512 + d0 + 4, *((unsigned long long*)ov + 1));
    } else {
        *(int4*)(ctx + (size_t)m * 512 + d0) = *(int4*)ov;
    }
}

// ---------------- scan role (shared): v10/v11 structure, HW-proven sync ----------------
template<int WRITE_ALL>
DEV void scan_role(char* smem, int cb, int rg,
                   const short* xW, const short* Wp, const float* bh,
                   short* hb0, short* hb1, short* h_all, float* h_final,
                   unsigned* done, unsigned* slice_cnt, int tps, int S, int T)
{
    char* wl = smem;               // 96 KB Wh fragments
    char* sl = smem + 98304;       // 32 KB h slab, XOR-swizzled
    char* ho = smem + 131072;      // 32 x 72B out tile
    int tid = threadIdx.x;
    int r0 = rg * 32;
    int w = tid >> 6, l = tid & 63;
    int rt = w >> 1, ct = w & 1;
    int lrow = l & 15, lq = l >> 4;
    int colg = cb * 32 + ct * 16 + lrow;
    unsigned* mydone = done + rg * 32;

    for (int rr = 0; rr < 24; rr++) {
        int flat = rr * 256 + tid;
        int lane = flat & 63, kk = (flat >> 6) & 15, lg = flat >> 10;
        int g = lg >> 1, c2 = lg & 1;
        gload_lds16(Wp + (((size_t)(g * 32 + cb * 2 + c2) * 16 + kk) * 64 + lane) * 8,
                    wl + flat * 16);
    }
    float bhv[3];
#pragma unroll
    for (int g = 0; g < 3; g++) bhv[g] = bh[g * 512 + colg];
    __syncthreads();   // drains Wh DMA

    float hp[4] = {};

    for (int t = 0; t < T; t++) {
        if (tid < 16) {
            if (t > 0)
                while (ald(&mydone[tid]) < (unsigned)t) __builtin_amdgcn_s_sleep(1);
        } else if (tid == 16) {
            while (ald(&slice_cnt[t]) < (unsigned)tps) __builtin_amdgcn_s_sleep(1);
        }
        __syncthreads();

        short xrv[4], xzv[4], xnv[4];
        const short* xbase = xW + ((size_t)t * S + r0) * 1536 + colg;
#pragma unroll
        for (int j = 0; j < 4; j++) {
            const short* xp = xbase + (size_t)(rt * 16 + lq * 4 + j) * 1536;
            xrv[j] = xp[0]; xzv[j] = xp[512]; xnv[j] = xp[1024];
        }

        f32x4 acc[3] = {};
        if (t > 0) {
            const short* hprev = ((t & 1) ? hb0 : hb1) + (size_t)r0 * 512;
            unsigned long long v[16];
            const unsigned long long* sp = (const unsigned long long*)hprev;
#pragma unroll
            for (int k = 0; k < 16; k++)
                v[k] = ald64(sp + k * 256 + tid);
#pragma unroll
            for (int k = 0; k < 16; k++) {
                int off = (k * 256 + tid) * 8;
                int row = off >> 10, colb = off & 1023;
                *(unsigned long long*)(sl + row * 1024 + (colb ^ ((row & 7) << 4))) = v[k];
            }
            __syncthreads();
            bf16x8 afr[16];
            int ar = rt * 16 + lrow;
#pragma unroll
            for (int kk = 0; kk < 16; kk++) {
                int colb = kk * 64 + lq * 16;
                afr[kk] = *(const bf16x8*)(sl + ar * 1024 + (colb ^ ((ar & 7) << 4)));
            }
#pragma unroll
            for (int g = 0; g < 3; g++) {
                const char* bbase = wl + (size_t)((g * 2 + ct) * 16) * 1024 + l * 16;
#pragma unroll
                for (int kk = 0; kk < 16; kk++) {
                    bf16x8 bfr = *(const bf16x8*)(bbase + kk * 1024);
                    acc[g] = mfma16(afr[kk], bfr, acc[g]);
                }
            }
        }

        float hv[4];
#pragma unroll
        for (int j = 0; j < 4; j++) {
            float r = sigmoidf_(bf2f(xrv[j]) + bhv[0] + acc[0][j]);
            float z = sigmoidf_(bf2f(xzv[j]) + bhv[1] + acc[1][j]);
            float n = tanhf_(bf2f(xnv[j]) + r * (acc[2][j] + bhv[2]));
            hv[j] = (1.f - z) * n + z * hp[j];
            hp[j] = hv[j];
            *(short*)(ho + (rt * 16 + lq * 4 + j) * 72 + (ct * 16 + lrow) * 2) = f2bf(hv[j]);
        }
        __syncthreads();
        {
            int row = tid >> 3, ch = tid & 7;
            unsigned long long val = *(const unsigned long long*)(ho + row * 72 + ch * 8);
            short* hnew = (t & 1) ? hb1 : hb0;
            ast64(hnew + (size_t)(r0 + row) * 512 + cb * 32 + ch * 4, val);
            if (WRITE_ALL)
                *(unsigned long long*)(h_all + ((size_t)t * S + r0 + row) * 512 + cb * 32 + ch * 4) = val;
        }
        if (!WRITE_ALL && t == T - 1) {
#pragma unroll
            for (int j = 0; j < 4; j++)
                h_final[(size_t)(r0 + rt * 16 + lq * 4 + j) * 512 + colg] = hv[j];
        }
        __syncthreads();
        if (tid == 0)
            ast32(&mydone[cb], (unsigned)(t + 1));
    }
}

// ---------------- GRU1 fused: 128 scan + 128 producers (xW1 then word attention) -------
__global__ __launch_bounds__(256, 1) void gru_fused1(
    short* xW1, const short* __restrict__ Wp, const float* __restrict__ bh,
    short* __restrict__ hb0, short* __restrict__ hb1, short* __restrict__ h_all,
    unsigned* done, unsigned* slc,
    const short* __restrict__ embed_bf, const int* __restrict__ ask,
    const int* __restrict__ answer, const short* __restrict__ Wi1b,
    const float* __restrict__ bi1,
    const int* __restrict__ askkw, const int* __restrict__ anskw,
    const short* __restrict__ Awb, const float* __restrict__ bw,
    float* usumW, short* uAb, const float* __restrict__ Ww, short* ctxW,
    unsigned* wcnt)
{
    __shared__ char smem[133376];
    int bid = blockIdx.x, tid = threadIdx.x;

    if (bid >= 128) {
        int pid = bid - 128;
        short* Als = (short*)smem;
        short* Bls = (short*)(smem + 16384);
        short* Ct  = (short*)(smem + 32768);
        // xW1: 256 slices x 24 tiles, slice-ordered
        for (int q = pid; q < 256 * 24; q += 128) {
            int slice = q / 24, j = q % 24;
            int m0 = (slice * 2 + (j >= 12 ? 1 : 0)) * 128, n0 = (j % 12) * 128;
            gemm_tile<A_XW1>(Als, Bls, Ct, m0, n0, embed_bf, nullptr, ask, answer,
                             Wi1b, bi1, xW1, 1536, 512);
            if (tid == 0) aadd(&slc[slice], 1u);
        }
        // word attention (independent of GRU1; hidden under the scan)
        embed_sum_dev(embed_bf, askkw, usumW, pid);
        for (int k = 0; k < 8; k++) {
            int q = pid + k * 128;   // 1024 tiles of uA = ask_kw @ Aw^T + bw
            gemm_tile<A_UAW>(Als, Bls, Ct, (q >> 2) * 128, (q & 3) * 128,
                             embed_bf, nullptr, askkw, nullptr, Awb, bw, uAb, 512, 512);
        }
        if (tid == 0) {
            aadd(wcnt, 1u);
            while (ald(wcnt) < 128u) __builtin_amdgcn_s_sleep(1);
        }
        __syncthreads();
        for (int bb = pid * 64; bb < pid * 64 + 64; bb++)
            combine4<1, 0>(bb, uAb, embed_bf, anskw, usumW, Ww, ctxW);
        return;
    }
    scan_role<1>(smem, bid & 15, bid >> 4, xW1, Wp, bh, hb0, hb1, h_all, nullptr,
                 done, slc, 24, 256, 256);
}

// ---------------- GRU2 fused: seq-attention pre-phase (all 256) + 64 scan + 192 prod ----
__global__ __launch_bounds__(256, 1) void gru_fused2(
    short* xW2, const short* __restrict__ Wp, const float* __restrict__ bh,
    short* __restrict__ hb0, short* __restrict__ hb1, float* __restrict__ h_final,
    unsigned* done, unsigned* slc,
    const short* __restrict__ h_all, float* usumS, short* uAb,
    const short* __restrict__ Asb, const float* __restrict__ bs,
    const float* __restrict__ Ws, short* ctxS, const short* __restrict__ ctxW,
    const short* __restrict__ Wi2b, const float* __restrict__ bi2,
    unsigned* acnt, unsigned* ccnt)
{
    __shared__ char smem[133376];
    int bid = blockIdx.x, tid = threadIdx.x;
    short* Als = (short*)smem;
    short* Bls = (short*)(smem + 16384);
    short* Ct  = (short*)(smem + 32768);

    // pre-phase: seq attention on all 256 wgs
    if (bid < 128) hall_sum_dev(h_all, usumS, bid);
    for (int k = 0; k < 4; k++) {
        int q = bid + k * 256;   // 1024 tiles of uA = h_ask @ As^T + bs
        gemm_tile<A_UAS>(Als, Bls, Ct, (q >> 2) * 128, (q & 3) * 128,
                         h_all, nullptr, nullptr, nullptr, Asb, bs, uAb, 512, 512);
    }
    if (tid == 0) {
        aadd(acnt, 1u);
        while (ald(acnt) < 256u) __builtin_amdgcn_s_sleep(1);
    }
    __syncthreads();
    for (int bb = bid * 32; bb < bid * 32 + 32; bb++)
        combine4<0, 1>(bb, uAb, h_all, nullptr, usumS, Ws, ctxS);
    __syncthreads();                 // per-thread vmcnt(0): ctxS coherent stores drained
    if (tid == 0) aadd(ccnt, 1u);

    if (bid >= 64) {
        int pid = bid - 64;
        if (tid == 0) { while (ald(ccnt) < 256u) __builtin_amdgcn_s_sleep(1); }
        __syncthreads();
        for (int q = pid; q < 256 * 12; q += 192) {
            int slice = q / 12, j = q % 12;
            gemm_tile<A_XW2>(Als, Bls, Ct, slice * 128, j * 128,
                             ctxW, ctxS, nullptr, nullptr, Wi2b, bi2, xW2, 1536, 1024);
            if (tid == 0) aadd(&slc[slice], 1u);
        }
        return;
    }
    scan_role<0>(smem, bid & 15, bid >> 4, xW2, Wp, bh, hb0, hb1, nullptr, h_final,
                 done, slc, 12, 128, 256);
}

// ---------------- final classifier + softmax ----------------
__global__ void final_head_k(const float* __restrict__ h2, const float* __restrict__ Wf,
                             const float* __restrict__ bfv, float* __restrict__ out) {
    int b = blockIdx.x, l = threadIdx.x;  // 64 threads
    float d0 = 0.f, d1 = 0.f;
    for (int k = l; k < 512; k += 64) {
        float h = h2[b * 512 + k];
        d0 += h * Wf[k];
        d1 += h * Wf[512 + k];
    }
#pragma unroll
    for (int off = 32; off >= 1; off >>= 1) { d0 += __shfl_xor(d0, off); d1 += __shfl_xor(d1, off); }
    if (l == 0) {
        float l0 = d0 + bfv[0], l1 = d1 + bfv[1];
        float mx = fmaxf(l0, l1);
        float e0 = __expf(l0 - mx), e1 = __expf(l1 - mx);
        float s = e0 + e1;
        out[b * 2] = e0 / s; out[b * 2 + 1] = e1 / s;
    }
}

extern "C" void kernel_launch(void* const* d_in, const int* in_sizes, int n_in,
                              void* d_out, int out_size, void* d_ws, size_t ws_size,
                              hipStream_t stream)
{
    const int* ask    = (const int*)d_in[0];
    const int* answer = (const int*)d_in[1];
    const int* askkw  = (const int*)d_in[2];
    const int* anskw  = (const int*)d_in[3];
    const float* embed = (const float*)d_in[4];
    const float* Wi1 = (const float*)d_in[5];
    const float* Wh1 = (const float*)d_in[6];
    const float* bi1 = (const float*)d_in[7];
    const float* bh1 = (const float*)d_in[8];
    const float* Aw  = (const float*)d_in[9];
    const float* bw  = (const float*)d_in[10];
    const float* Ww  = (const float*)d_in[11];
    const float* As  = (const float*)d_in[12];
    const float* bs  = (const float*)d_in[13];
    const float* Ws  = (const float*)d_in[14];
    const float* Wi2 = (const float*)d_in[15];
    const float* Wh2 = (const float*)d_in[16];
    const float* bi2 = (const float*)d_in[17];
    const float* bh2 = (const float*)d_in[18];
    const float* Wf  = (const float*)d_in[19];
    const float* bfv = (const float*)d_in[20];

    char* ws = (char*)d_ws;
    size_t off = 0;
    auto alloc = [&](size_t bytes) -> void* {
        void* p = (void*)(ws + off);
        off += (bytes + 255) & ~(size_t)255;
        return p;
    };
    short* embed_bf = (short*)alloc(50000ULL * 512 * 2);
    short* Wi1b = (short*)alloc(1536 * 512 * 2);
    short* Wp1  = (short*)alloc(1536 * 512 * 2);
    short* Awb  = (short*)alloc(512 * 512 * 2);
    short* Asb  = (short*)alloc(512 * 512 * 2);
    short* Wi2b = (short*)alloc(1536 * 1024 * 2);
    short* Wp2  = (short*)alloc(1536 * 512 * 2);
    char* X = (char*)alloc(201326592ULL);            // xW1 [256][256][1536] bf16
    short* xW1  = (short*)X;
    short* xW2  = (short*)X;                         // [256][128][1536] bf16 (xW1 dead)
    short* ctxS = (short*)(X + 100663296);           // X tail: written in gru_fused2
                                                     // pre-phase, AFTER xW1 is dead and
                                                     // outside xW2's front 100.7 MB
    short* uAb  = (short*)alloc(32768ULL * 512 * 2); // uA (word attn, then seq attn)
    short* ctxW = (short*)alloc(32768ULL * 512 * 2); // live across both fused kernels
    short* h_all = (short*)alloc(256ULL * 256 * 512 * 2);
    short* hb0 = (short*)alloc(256 * 512 * 2);
    short* hb1 = (short*)alloc(256 * 512 * 2);
    float* usumW = (float*)alloc(128 * 512 * 4);
    float* usumS = (float*)alloc(128 * 512 * 4);
    float* h2f   = (float*)alloc(128 * 512 * 4);
    unsigned* syncb = (unsigned*)alloc((8 * 32 + 4 * 32 + 256 + 256 + 96) * 4);
    unsigned* done1 = syncb;
    unsigned* done2 = syncb + 8 * 32;
    unsigned* slc1  = syncb + 12 * 32;
    unsigned* slc2  = slc1 + 256;
    unsigned* wcnt1 = slc2 + 256;
    unsigned* acnt2 = wcnt1 + 32;
    unsigned* ccnt2 = wcnt1 + 64;

    if (off > ws_size) {
        fprintf(stderr, "kernel_launch: workspace too small: need %zu have %zu\n", off, ws_size);
        return;
    }

    hipMemsetAsync(syncb, 0, (8 * 32 + 4 * 32 + 256 + 256 + 96) * 4, stream);

    auto cv = [&](const float* src, short* dst, int n) {
        int n4 = n / 4;
        f2bf_vec<<<(n4 + 255) / 256, 256, 0, stream>>>(src, dst, n4);
    };
    cv(embed, embed_bf, 50000 * 512);
    cv(Wi1, Wi1b, 1536 * 512);
    cv(Aw, Awb, 512 * 512);
    cv(As, Asb, 512 * 512);
    cv(Wi2, Wi2b, 1536 * 1024);
    pack_wh<<<dim3(96, 16), 64, 0, stream>>>(Wh1, Wp1);
    pack_wh<<<dim3(96, 16), 64, 0, stream>>>(Wh2, Wp2);

    // GRU1 + xW1 producers + word attention
    {
        void* args[] = { (void*)&xW1, (void*)&Wp1, (void*)&bh1, (void*)&hb0, (void*)&hb1,
                         (void*)&h_all, (void*)&done1, (void*)&slc1,
                         (void*)&embed_bf, (void*)&ask, (void*)&answer, (void*)&Wi1b, (void*)&bi1,
                         (void*)&askkw, (void*)&anskw, (void*)&Awb, (void*)&bw,
                         (void*)&usumW, (void*)&uAb, (void*)&Ww, (void*)&ctxW, (void*)&wcnt1 };
        hipError_t e = hipLaunchCooperativeKernel(
            reinterpret_cast<void*>(&gru_fused1), dim3(256), dim3(256), args, 0, stream);
        if (e != hipSuccess)
            gru_fused1<<<256, 256, 0, stream>>>(
                xW1, Wp1, bh1, hb0, hb1, h_all, done1, slc1,
                embed_bf, ask, answer, Wi1b, bi1,
                askkw, anskw, Awb, bw, usumW, uAb, Ww, ctxW, wcnt1);
    }

    // GRU2 + seq-attention pre-phase + xW2 producers
    {
        void* args[] = { (void*)&xW2, (void*)&Wp2, (void*)&bh2, (void*)&hb0, (void*)&hb1,
                         (void*)&h2f, (void*)&done2, (void*)&slc2,
                         (void*)&h_all, (void*)&usumS, (void*)&uAb,
                         (void*)&Asb, (void*)&bs, (void*)&Ws, (void*)&ctxS, (void*)&ctxW,
                         (void*)&Wi2b, (void*)&bi2, (void*)&acnt2, (void*)&ccnt2 };
        hipError_t e = hipLaunchCooperativeKernel(
            reinterpret_cast<void*>(&gru_fused2), dim3(256), dim3(256), args, 0, stream);
        if (e != hipSuccess)
            gru_fused2<<<256, 256, 0, stream>>>(
                xW2, Wp2, bh2, hb0, hb1, h2f, done2, slc2,
                h_all, usumS, uAb, Asb, bs, Ws, ctxS, ctxW, Wi2b, bi2, acnt2, ccnt2);
    }

    final_head_k<<<128, 64, 0, stream>>>(h2f, Wf, bfv, (float*)d_out);
}